// Round 3
// baseline (995.432 us; speedup 1.0000x reference)
//
#include <hip/hip_runtime.h>

#define S_LEN 2048
#define DMODEL 1024
#define NH 16
#define DK 64
#define BATCH 2
#define BS (BATCH * S_LEN)  // 4096

typedef _Float16 f16;
typedef _Float16 f16x8 __attribute__((ext_vector_type(8)));
typedef _Float16 f16x4 __attribute__((ext_vector_type(4)));
typedef float f32x4 __attribute__((ext_vector_type(4)));

__device__ __forceinline__ f32x4 mfma16(f16x8 a, f16x8 b, f32x4 c) {
  return __builtin_amdgcn_mfma_f32_16x16x32_f16(a, b, c, 0, 0, 0);
}

// ---------------------------------------------------------------------------
// Pre-convert fp32 -> f16 for all GEMM operands (activations + weights).
// y: 0=q 1=k 2=v (BS*DMODEL), 3=w_q 4=w_v 5=w_o (DMODEL*DMODEL).
// Done ONCE so GEMMs never touch fp32 / never re-convert per tile.
// ---------------------------------------------------------------------------
__global__ __launch_bounds__(256) void cvt6(
    const float* __restrict__ a0, const float* __restrict__ a1,
    const float* __restrict__ a2, const float* __restrict__ a3,
    const float* __restrict__ a4, const float* __restrict__ a5,
    f16* __restrict__ d0, f16* __restrict__ d1, f16* __restrict__ d2,
    f16* __restrict__ d3, f16* __restrict__ d4, f16* __restrict__ d5) {
  const int y = blockIdx.y;
  const float* s;
  f16* d;
  switch (y) {
    case 0: s = a0; d = d0; break;
    case 1: s = a1; d = d1; break;
    case 2: s = a2; d = d2; break;
    case 3: s = a3; d = d3; break;
    case 4: s = a4; d = d4; break;
    default: s = a5; d = d5; break;
  }
  const int n = (y < 3) ? BS * DMODEL : DMODEL * DMODEL;
  const int idx = (blockIdx.x * 256 + threadIdx.x) * 4;
  if (idx >= n) return;
  const float4 v = *reinterpret_cast<const float4*>(&s[idx]);
  f16x4 h = {(f16)v.x, (f16)v.y, (f16)v.z, (f16)v.w};
  *reinterpret_cast<f16x4*>(&d[idx]) = h;
}

// ---------------------------------------------------------------------------
// All-f16 NT GEMM, BK=64 (half the barriers of the old BK=32 fp32-cvt path).
// C[M=4096][N=1024] = (A[4096][1024] * W[1024][1024]^T + bias) * scale
// MODE 0: f16 head-split [B][H][S][DK]; MODE 1: f16 [B][H][DK][S];
// MODE 2: fp32 row-major.
// ---------------------------------------------------------------------------
template <int MODE>
__device__ __forceinline__ void gemm_body16(const f16* __restrict__ A,
                                            const f16* __restrict__ W,
                                            const float* __restrict__ bias,
                                            void* __restrict__ outp, float scale,
                                            f16 (*As)[72], f16 (*Ws)[72]) {
  const int t = threadIdx.x;
  const int m0 = blockIdx.y * 128;
  const int n0 = blockIdx.x * 128;
  const int wave = t >> 6, lane = t & 63;
  const int wr = wave >> 1, wc = wave & 1;
  const int lcol = lane & 15, kq = lane >> 4;

  f32x4 acc[4][4];
  const f32x4 zero = {0.f, 0.f, 0.f, 0.f};
#pragma unroll
  for (int i = 0; i < 4; ++i)
#pragma unroll
    for (int j = 0; j < 4; ++j) acc[i][j] = zero;

  for (int k0 = 0; k0 < DMODEL; k0 += 64) {
#pragma unroll
    for (int i = 0; i < 4; ++i) {
      const int f = t + i * 256;
      const int r = f >> 3, c = (f & 7) << 3;
      *reinterpret_cast<f16x8*>(&As[r][c]) =
          *reinterpret_cast<const f16x8*>(&A[(size_t)(m0 + r) * DMODEL + k0 + c]);
      *reinterpret_cast<f16x8*>(&Ws[r][c]) =
          *reinterpret_cast<const f16x8*>(&W[(size_t)(n0 + r) * DMODEL + k0 + c]);
    }
    __syncthreads();
#pragma unroll
    for (int ks = 0; ks < 2; ++ks) {
      f16x8 af[4], bf[4];
#pragma unroll
      for (int fr = 0; fr < 4; ++fr)
        af[fr] = *reinterpret_cast<const f16x8*>(
            &As[wr * 64 + fr * 16 + lcol][ks * 32 + kq * 8]);
#pragma unroll
      for (int fc = 0; fc < 4; ++fc)
        bf[fc] = *reinterpret_cast<const f16x8*>(
            &Ws[wc * 64 + fc * 16 + lcol][ks * 32 + kq * 8]);
#pragma unroll
      for (int fr = 0; fr < 4; ++fr)
#pragma unroll
        for (int fc = 0; fc < 4; ++fc)
          acc[fr][fc] = mfma16(af[fr], bf[fc], acc[fr][fc]);
    }
    __syncthreads();
  }

#pragma unroll
  for (int fc = 0; fc < 4; ++fc) {
    const int gj = n0 + wc * 64 + fc * 16 + lcol;
    const float bv = bias[gj];
#pragma unroll
    for (int fr = 0; fr < 4; ++fr) {
#pragma unroll
      for (int r = 0; r < 4; ++r) {
        const int gi = m0 + wr * 64 + fr * 16 + kq * 4 + r;
        const float val = (acc[fr][fc][r] + bv) * scale;
        if constexpr (MODE == 0) {
          const int b = gi >> 11, s = gi & 2047, h = gj >> 6, dk = gj & 63;
          ((f16*)outp)[(((size_t)(b * NH + h) * S_LEN) + s) * DK + dk] = (f16)val;
        } else if constexpr (MODE == 1) {
          const int b = gi >> 11, s = gi & 2047, h = gj >> 6, dk = gj & 63;
          ((f16*)outp)[(((size_t)(b * NH + h) * DK) + dk) * S_LEN + s] = (f16)val;
        } else {
          ((float*)outp)[(size_t)gi * DMODEL + gj] = val;
        }
      }
    }
  }
}

// Fused q/k/v projections (z selects). q output pre-scaled by 1/sqrt(DK).
__global__ __launch_bounds__(256, 2) void qkv_gemm(
    const f16* __restrict__ qf, const f16* __restrict__ kf,
    const f16* __restrict__ vf, const f16* __restrict__ wq,
    const float* __restrict__ b_q, const f16* __restrict__ wv,
    const float* __restrict__ b_v, f16* __restrict__ qh, f16* __restrict__ kh,
    f16* __restrict__ vhT) {
  __shared__ f16 As[128][72];
  __shared__ f16 Ws[128][72];
  if (blockIdx.z == 0)
    gemm_body16<0>(qf, wq, b_q, qh, 0.125f, As, Ws);
  else if (blockIdx.z == 1)
    gemm_body16<0>(kf, wq, b_q, kh, 1.0f, As, Ws);
  else
    gemm_body16<1>(vf, wv, b_v, vhT, 1.0f, As, Ws);
}

__global__ __launch_bounds__(256, 2) void gemm_out(const f16* __restrict__ A,
                                                   const f16* __restrict__ W,
                                                   const float* __restrict__ bias,
                                                   float* __restrict__ outp) {
  __shared__ f16 As[128][72];
  __shared__ f16 Ws[128][72];
  gemm_body16<2>(A, W, bias, outp, 1.0f, As, Ws);
}

// ---------------------------------------------------------------------------
// Fused attention: one kernel, two sweeps over K, 64 query rows per block
// (grid 32x32 = 1024 blocks, 4 blocks/CU for latency hiding).
// Sweep 1: s = qk (MFMA), pun = exp(s) masked; accumulate l AND unnormalized
//          O_un = sum pun*V  (softmax identity: O = O_un / l -> PV needs no l).
// Sweep 2: recompute s bit-identically, write attn = exp(s)*(1/l) fp32.
// l never leaves registers. K/V direct from global (L2-resident).
// ---------------------------------------------------------------------------
__global__ __launch_bounds__(256, 4) void attn_fused(
    const f16* __restrict__ qh, const f16* __restrict__ kh,
    const f16* __restrict__ vhT, const int* __restrict__ mask,
    float* __restrict__ attn, f16* __restrict__ ctx) {
  __shared__ f16 Ps[4][16][72];  // per-wave P tile (f16), C-layout -> A-layout
  __shared__ int msk[S_LEN];
  const int t = threadIdx.x;
  const int bh = blockIdx.y, b = bh >> 4, h = bh & 15;
  const int i0 = blockIdx.x * 64;
  const int wave = t >> 6, lane = t & 63;
  const int lcol = lane & 15, kq = lane >> 4;
  const int rbase = i0 + wave * 16;
  const f16* Q = qh + (size_t)bh * S_LEN * DK;
  const f16* K = kh + (size_t)bh * S_LEN * DK;
  const f16* V = vhT + (size_t)bh * DK * S_LEN;
  float* Sc = attn + (size_t)bh * S_LEN * S_LEN;

  for (int i = t; i < S_LEN; i += 256) msk[i] = mask[b * S_LEN + i];

  f16x8 aq[2];
#pragma unroll
  for (int ks = 0; ks < 2; ++ks)
    aq[ks] = *reinterpret_cast<const f16x8*>(
        &Q[(size_t)(rbase + lcol) * DK + ks * 32 + kq * 8]);

  float l_acc[4] = {0.f, 0.f, 0.f, 0.f};
  f32x4 o[4];
  const f32x4 zero = {0.f, 0.f, 0.f, 0.f};
#pragma unroll
  for (int d = 0; d < 4; ++d) o[d] = zero;

  __syncthreads();  // msk ready (only barrier)

  // ---- sweep 1: l + unnormalized PV ----
  for (int j0 = 0; j0 < S_LEN; j0 += 64) {
#pragma unroll
    for (int jt = 0; jt < 4; ++jt) {
      const f16* Krow = &K[(size_t)(j0 + jt * 16 + lcol) * DK + kq * 8];
      const f16x8 bk0 = *reinterpret_cast<const f16x8*>(Krow);
      const f16x8 bk1 = *reinterpret_cast<const f16x8*>(Krow + 32);
      const int mv = msk[j0 + jt * 16 + lcol];
      f32x4 c = zero;
      c = mfma16(aq[0], bk0, c);
      c = mfma16(aq[1], bk1, c);
#pragma unroll
      for (int r = 0; r < 4; ++r) {
        const float pun = mv ? __expf(c[r]) : 0.f;
        l_acc[r] += pun;
        Ps[wave][kq * 4 + r][jt * 16 + lcol] = (f16)pun;
      }
    }
#pragma unroll
    for (int ks = 0; ks < 2; ++ks) {
      const f16x8 ap =
          *reinterpret_cast<const f16x8*>(&Ps[wave][lcol][ks * 32 + kq * 8]);
      f16x8 bv[4];
#pragma unroll
      for (int d = 0; d < 4; ++d)
        bv[d] = *reinterpret_cast<const f16x8*>(
            &V[(size_t)(d * 16 + lcol) * S_LEN + j0 + ks * 32 + kq * 8]);
#pragma unroll
      for (int d = 0; d < 4; ++d) o[d] = mfma16(ap, bv[d], o[d]);
    }
  }

  // ---- 16-lane row-sum reduce, l stays in registers ----
  float il[4];
#pragma unroll
  for (int r = 0; r < 4; ++r) {
    float es = l_acc[r];
#pragma unroll
    for (int off = 1; off < 16; off <<= 1) es += __shfl_xor(es, off);
    il[r] = 1.0f / es;
  }

  // ---- sweep 2: recompute (bit-identical), write attn fp32-exact ----
  for (int j0 = 0; j0 < S_LEN; j0 += 64) {
#pragma unroll
    for (int jt = 0; jt < 4; ++jt) {
      const f16* Krow = &K[(size_t)(j0 + jt * 16 + lcol) * DK + kq * 8];
      const f16x8 bk0 = *reinterpret_cast<const f16x8*>(Krow);
      const f16x8 bk1 = *reinterpret_cast<const f16x8*>(Krow + 32);
      const int mv = msk[j0 + jt * 16 + lcol];
      f32x4 c = zero;
      c = mfma16(aq[0], bk0, c);
      c = mfma16(aq[1], bk1, c);
#pragma unroll
      for (int r = 0; r < 4; ++r) {
        const float p = mv ? __expf(c[r]) * il[r] : 0.f;
        Sc[((size_t)(rbase + kq * 4 + r) << 11) + j0 + jt * 16 + lcol] = p;
      }
    }
  }

  // ---- epilogue: ctx = O_un * (1/l) ----
#pragma unroll
  for (int d = 0; d < 4; ++d) {
    const int dk = d * 16 + lcol;
#pragma unroll
    for (int r = 0; r < 4; ++r) {
      const int s = rbase + kq * 4 + r;
      ctx[(size_t)(b * S_LEN + s) * DMODEL + h * DK + dk] = (f16)(o[d][r] * il[r]);
    }
  }
}

extern "C" void kernel_launch(void* const* d_in, const int* in_sizes, int n_in,
                              void* d_out, int out_size, void* d_ws, size_t ws_size,
                              hipStream_t stream) {
  const float* q = (const float*)d_in[0];
  const float* k = (const float*)d_in[1];
  const float* v = (const float*)d_in[2];
  const int* mask = (const int*)d_in[3];
  const float* w_q = (const float*)d_in[4];
  const float* b_q = (const float*)d_in[5];
  const float* w_v = (const float*)d_in[6];
  const float* b_v = (const float*)d_in[7];
  const float* w_o = (const float*)d_in[8];
  const float* b_o = (const float*)d_in[9];

  float* out = (float*)d_out;
  float* attn = out + (size_t)BS * DMODEL;  // output 1 region

  // workspace (all f16): converted inputs, converted weights, intermediates
  f16* qf = (f16*)d_ws;                      // [BS][DMODEL]
  f16* kf = qf + (size_t)BS * DMODEL;
  f16* vf = kf + (size_t)BS * DMODEL;
  f16* wqf = vf + (size_t)BS * DMODEL;       // [DMODEL][DMODEL]
  f16* wvf = wqf + (size_t)DMODEL * DMODEL;
  f16* wof = wvf + (size_t)DMODEL * DMODEL;
  f16* qh = wof + (size_t)DMODEL * DMODEL;   // [B][H][S][DK] (pre-scaled 0.125)
  f16* kh = qh + (size_t)BS * DMODEL;        // [B][H][S][DK]
  f16* vhT = kh + (size_t)BS * DMODEL;       // [B][H][DK][S]
  f16* ctx = vhT + (size_t)BS * DMODEL;      // [BS][DMODEL]

  cvt6<<<dim3(4096, 6), 256, 0, stream>>>(q, k, v, w_q, w_v, w_o, qf, kf, vf,
                                          wqf, wvf, wof);
  qkv_gemm<<<dim3(8, 32, 3), 256, 0, stream>>>(qf, kf, vf, wqf, b_q, wvf, b_v,
                                               qh, kh, vhT);
  attn_fused<<<dim3(32, 32), 256, 0, stream>>>(qh, kh, vhT, mask, attn, ctx);
  gemm_out<<<dim3(8, 32), 256, 0, stream>>>(ctx, wof, b_o, out);
}

// Round 4
// 932.329 us; speedup vs baseline: 1.0677x; 1.0677x over previous
//
#include <hip/hip_runtime.h>

#define S_LEN 2048
#define DMODEL 1024
#define NH 16
#define DK 64
#define BATCH 2
#define BS (BATCH * S_LEN)  // 4096
#define KHALF 1024

typedef _Float16 f16;
typedef _Float16 f16x8 __attribute__((ext_vector_type(8)));
typedef _Float16 f16x4 __attribute__((ext_vector_type(4)));
typedef float f32x4 __attribute__((ext_vector_type(4)));

__device__ __forceinline__ f32x4 mfma16(f16x8 a, f16x8 b, f32x4 c) {
  return __builtin_amdgcn_mfma_f32_16x16x32_f16(a, b, c, 0, 0, 0);
}

// ---------------------------------------------------------------------------
// Pre-convert fp32 -> f16 for all GEMM operands (activations + weights).
// ---------------------------------------------------------------------------
__global__ __launch_bounds__(256) void cvt6(
    const float* __restrict__ a0, const float* __restrict__ a1,
    const float* __restrict__ a2, const float* __restrict__ a3,
    const float* __restrict__ a4, const float* __restrict__ a5,
    f16* __restrict__ d0, f16* __restrict__ d1, f16* __restrict__ d2,
    f16* __restrict__ d3, f16* __restrict__ d4, f16* __restrict__ d5) {
  const int y = blockIdx.y;
  const float* s;
  f16* d;
  switch (y) {
    case 0: s = a0; d = d0; break;
    case 1: s = a1; d = d1; break;
    case 2: s = a2; d = d2; break;
    case 3: s = a3; d = d3; break;
    case 4: s = a4; d = d4; break;
    default: s = a5; d = d5; break;
  }
  const int n = (y < 3) ? BS * DMODEL : DMODEL * DMODEL;
  const int idx = (blockIdx.x * 256 + threadIdx.x) * 4;
  if (idx >= n) return;
  const float4 v = *reinterpret_cast<const float4*>(&s[idx]);
  f16x4 h = {(f16)v.x, (f16)v.y, (f16)v.z, (f16)v.w};
  *reinterpret_cast<f16x4*>(&d[idx]) = h;
}

// ---------------------------------------------------------------------------
// All-f16 NT GEMM, BK=64.
// MODE 0: f16 head-split [B][H][S][DK]; MODE 1: f16 [B][H][DK][S];
// MODE 2: fp32 row-major.
// ---------------------------------------------------------------------------
template <int MODE>
__device__ __forceinline__ void gemm_body16(const f16* __restrict__ A,
                                            const f16* __restrict__ W,
                                            const float* __restrict__ bias,
                                            void* __restrict__ outp, float scale,
                                            f16 (*As)[72], f16 (*Ws)[72]) {
  const int t = threadIdx.x;
  const int m0 = blockIdx.y * 128;
  const int n0 = blockIdx.x * 128;
  const int wave = t >> 6, lane = t & 63;
  const int wr = wave >> 1, wc = wave & 1;
  const int lcol = lane & 15, kq = lane >> 4;

  f32x4 acc[4][4];
  const f32x4 zero = {0.f, 0.f, 0.f, 0.f};
#pragma unroll
  for (int i = 0; i < 4; ++i)
#pragma unroll
    for (int j = 0; j < 4; ++j) acc[i][j] = zero;

  for (int k0 = 0; k0 < DMODEL; k0 += 64) {
#pragma unroll
    for (int i = 0; i < 4; ++i) {
      const int f = t + i * 256;
      const int r = f >> 3, c = (f & 7) << 3;
      *reinterpret_cast<f16x8*>(&As[r][c]) =
          *reinterpret_cast<const f16x8*>(&A[(size_t)(m0 + r) * DMODEL + k0 + c]);
      *reinterpret_cast<f16x8*>(&Ws[r][c]) =
          *reinterpret_cast<const f16x8*>(&W[(size_t)(n0 + r) * DMODEL + k0 + c]);
    }
    __syncthreads();
#pragma unroll
    for (int ks = 0; ks < 2; ++ks) {
      f16x8 af[4], bf[4];
#pragma unroll
      for (int fr = 0; fr < 4; ++fr)
        af[fr] = *reinterpret_cast<const f16x8*>(
            &As[wr * 64 + fr * 16 + lcol][ks * 32 + kq * 8]);
#pragma unroll
      for (int fc = 0; fc < 4; ++fc)
        bf[fc] = *reinterpret_cast<const f16x8*>(
            &Ws[wc * 64 + fc * 16 + lcol][ks * 32 + kq * 8]);
#pragma unroll
      for (int fr = 0; fr < 4; ++fr)
#pragma unroll
        for (int fc = 0; fc < 4; ++fc)
          acc[fr][fc] = mfma16(af[fr], bf[fc], acc[fr][fc]);
    }
    __syncthreads();
  }

#pragma unroll
  for (int fc = 0; fc < 4; ++fc) {
    const int gj = n0 + wc * 64 + fc * 16 + lcol;
    const float bv = bias[gj];
#pragma unroll
    for (int fr = 0; fr < 4; ++fr) {
#pragma unroll
      for (int r = 0; r < 4; ++r) {
        const int gi = m0 + wr * 64 + fr * 16 + kq * 4 + r;
        const float val = (acc[fr][fc][r] + bv) * scale;
        if constexpr (MODE == 0) {
          const int b = gi >> 11, s = gi & 2047, h = gj >> 6, dk = gj & 63;
          ((f16*)outp)[(((size_t)(b * NH + h) * S_LEN) + s) * DK + dk] = (f16)val;
        } else if constexpr (MODE == 1) {
          const int b = gi >> 11, s = gi & 2047, h = gj >> 6, dk = gj & 63;
          ((f16*)outp)[(((size_t)(b * NH + h) * DK) + dk) * S_LEN + s] = (f16)val;
        } else {
          ((float*)outp)[(size_t)gi * DMODEL + gj] = val;
        }
      }
    }
  }
}

// Fused q/k/v projections (z selects). q output pre-scaled by 1/sqrt(DK).
// (256,3): grid 768 -> 3 blocks/CU schedulable (LDS 36.9KB allows 4).
__global__ __launch_bounds__(256, 3) void qkv_gemm(
    const f16* __restrict__ qf, const f16* __restrict__ kf,
    const f16* __restrict__ vf, const f16* __restrict__ wq,
    const float* __restrict__ b_q, const f16* __restrict__ wv,
    const float* __restrict__ b_v, f16* __restrict__ qh, f16* __restrict__ kh,
    f16* __restrict__ vhT) {
  __shared__ f16 As[128][72];
  __shared__ f16 Ws[128][72];
  if (blockIdx.z == 0)
    gemm_body16<0>(qf, wq, b_q, qh, 0.125f, As, Ws);
  else if (blockIdx.z == 1)
    gemm_body16<0>(kf, wq, b_q, kh, 1.0f, As, Ws);
  else
    gemm_body16<1>(vf, wv, b_v, vhT, 1.0f, As, Ws);
}

__global__ __launch_bounds__(256, 2) void gemm_out(const f16* __restrict__ A,
                                                   const f16* __restrict__ W,
                                                   const float* __restrict__ bias,
                                                   float* __restrict__ outp) {
  __shared__ f16 As[128][72];
  __shared__ f16 Ws[128][72];
  gemm_body16<2>(A, W, bias, outp, 1.0f, As, Ws);
}

// ---------------------------------------------------------------------------
// Fused attention, in-block K-split for TLP*ILP:
//   block = 256 thr / 4 waves over 64 Q-rows; wave = (row-half, K-half):
//   32 rows x 1024 cols per wave -> rt=2 MFMA chains (ILP) AND 4096 waves
//   total (16 waves/CU at 4 blocks/CU).
// Sweep 1: per K-half: l_partial + unnormalized O_partial (softmax identity
//   O = (sum exp*V)/l). Cross-wave combine of l and O through LDS (Ps union).
// Sweep 2: recompute s for own K-half, write attn = exp(s)*il fp32-exact.
// K/V/mask direct from global (L2-resident). l never leaves the block.
// ---------------------------------------------------------------------------
__global__ __launch_bounds__(256, 4) void attn_fused(
    const f16* __restrict__ qh, const f16* __restrict__ kh,
    const f16* __restrict__ vhT, const int* __restrict__ mask,
    float* __restrict__ attn, f16* __restrict__ ctx) {
  // union: [phase A] Ps f16 [4 waves][32][72] (18432 B)
  //        [phase B] Ostage f32 [64][68] (17408 B) + lred f32 [2][64] (512 B)
  __shared__ __align__(16) unsigned char smem[18432];
  const int t = threadIdx.x;
  const int bh = blockIdx.y, b = bh >> 4, h = bh & 15;
  const int i0 = blockIdx.x * 64;
  const int wave = t >> 6, lane = t & 63;
  const int rh = wave & 1, khf = wave >> 1;
  const int lcol = lane & 15, kq = lane >> 4;
  const int rbase = i0 + rh * 32;
  const int jbase = khf * KHALF;
  f16 (*Ps)[72] = reinterpret_cast<f16(*)[72]>(smem + wave * 4608);
  float (*Ost)[68] = reinterpret_cast<float(*)[68]>(smem);
  float* lred = reinterpret_cast<float*>(smem + 17408);  // [2][64]

  const f16* Q = qh + (size_t)bh * S_LEN * DK;
  const f16* K = kh + (size_t)bh * S_LEN * DK;
  const f16* V = vhT + (size_t)bh * DK * S_LEN;
  const int* msk = mask + b * S_LEN;
  float* Sc = attn + (size_t)bh * S_LEN * S_LEN;

  f16x8 aq[2][2];
#pragma unroll
  for (int rt = 0; rt < 2; ++rt)
#pragma unroll
    for (int ks = 0; ks < 2; ++ks)
      aq[rt][ks] = *reinterpret_cast<const f16x8*>(
          &Q[(size_t)(rbase + rt * 16 + lcol) * DK + ks * 32 + kq * 8]);

  float l_acc[2][4];
  f32x4 o[2][4];
  const f32x4 zero = {0.f, 0.f, 0.f, 0.f};
#pragma unroll
  for (int rt = 0; rt < 2; ++rt) {
#pragma unroll
    for (int r = 0; r < 4; ++r) l_acc[rt][r] = 0.f;
#pragma unroll
    for (int d = 0; d < 4; ++d) o[rt][d] = zero;
  }

  // ---- sweep 1 (own K-half): l_partial + unnormalized PV ----
  for (int j0 = jbase; j0 < jbase + KHALF; j0 += 64) {
#pragma unroll
    for (int jt = 0; jt < 4; ++jt) {
      const f16* Krow = &K[(size_t)(j0 + jt * 16 + lcol) * DK + kq * 8];
      const f16x8 bk0 = *reinterpret_cast<const f16x8*>(Krow);
      const f16x8 bk1 = *reinterpret_cast<const f16x8*>(Krow + 32);
      const int mv = msk[j0 + jt * 16 + lcol];
#pragma unroll
      for (int rt = 0; rt < 2; ++rt) {
        f32x4 c = zero;
        c = mfma16(aq[rt][0], bk0, c);
        c = mfma16(aq[rt][1], bk1, c);
#pragma unroll
        for (int r = 0; r < 4; ++r) {
          const float pun = mv ? __expf(c[r]) : 0.f;
          l_acc[rt][r] += pun;
          Ps[rt * 16 + kq * 4 + r][jt * 16 + lcol] = (f16)pun;
        }
      }
    }
#pragma unroll
    for (int ks = 0; ks < 2; ++ks) {
      f16x8 ap[2], bv[4];
#pragma unroll
      for (int rt = 0; rt < 2; ++rt)
        ap[rt] = *reinterpret_cast<const f16x8*>(
            &Ps[rt * 16 + lcol][ks * 32 + kq * 8]);
#pragma unroll
      for (int d = 0; d < 4; ++d)
        bv[d] = *reinterpret_cast<const f16x8*>(
            &V[(size_t)(d * 16 + lcol) * S_LEN + j0 + ks * 32 + kq * 8]);
#pragma unroll
      for (int rt = 0; rt < 2; ++rt)
#pragma unroll
        for (int d = 0; d < 4; ++d) o[rt][d] = mfma16(ap[rt], bv[d], o[rt][d]);
    }
  }

  // ---- 16-lane reduce of l_partial over lcol ----
#pragma unroll
  for (int rt = 0; rt < 2; ++rt)
#pragma unroll
    for (int r = 0; r < 4; ++r) {
      float es = l_acc[rt][r];
#pragma unroll
      for (int off = 1; off < 16; off <<= 1) es += __shfl_xor(es, off);
      l_acc[rt][r] = es;
    }

  __syncthreads();  // all waves done with Ps -> safe to repurpose smem

  if (lcol == 0) {
#pragma unroll
    for (int rt = 0; rt < 2; ++rt)
#pragma unroll
      for (int r = 0; r < 4; ++r)
        lred[khf * 64 + rh * 32 + rt * 16 + kq * 4 + r] = l_acc[rt][r];
  }
  if (khf == 1) {  // stage K-half-1 O partials
#pragma unroll
    for (int rt = 0; rt < 2; ++rt)
#pragma unroll
      for (int d = 0; d < 4; ++d)
#pragma unroll
        for (int r = 0; r < 4; ++r)
          Ost[rh * 32 + rt * 16 + kq * 4 + r][d * 16 + lcol] = o[rt][d][r];
  }
  __syncthreads();  // lred + Ostage complete

  float il[2][4];
#pragma unroll
  for (int rt = 0; rt < 2; ++rt)
#pragma unroll
    for (int r = 0; r < 4; ++r) {
      const int rl = rh * 32 + rt * 16 + kq * 4 + r;
      il[rt][r] = 1.0f / (lred[rl] + lred[64 + rl]);
    }

  // ---- sweep 2 (own K-half): recompute, write attn fp32-exact ----
  for (int j0 = jbase; j0 < jbase + KHALF; j0 += 64) {
#pragma unroll
    for (int jt = 0; jt < 4; ++jt) {
      const f16* Krow = &K[(size_t)(j0 + jt * 16 + lcol) * DK + kq * 8];
      const f16x8 bk0 = *reinterpret_cast<const f16x8*>(Krow);
      const f16x8 bk1 = *reinterpret_cast<const f16x8*>(Krow + 32);
      const int mv = msk[j0 + jt * 16 + lcol];
#pragma unroll
      for (int rt = 0; rt < 2; ++rt) {
        f32x4 c = zero;
        c = mfma16(aq[rt][0], bk0, c);
        c = mfma16(aq[rt][1], bk1, c);
#pragma unroll
        for (int r = 0; r < 4; ++r) {
          const float p = mv ? __expf(c[r]) * il[rt][r] : 0.f;
          Sc[((size_t)(rbase + rt * 16 + kq * 4 + r) << 11) + j0 + jt * 16 +
             lcol] = p;
        }
      }
    }
  }

  // ---- epilogue: combine O halves, normalize, write ctx (khf==0 waves) ----
  if (khf == 0) {
#pragma unroll
    for (int rt = 0; rt < 2; ++rt)
#pragma unroll
      for (int d = 0; d < 4; ++d) {
        const int dk = d * 16 + lcol;
#pragma unroll
        for (int r = 0; r < 4; ++r) {
          const int rl = rh * 32 + rt * 16 + kq * 4 + r;
          const float ov = o[rt][d][r] + Ost[rl][dk];
          const int s = rbase + rt * 16 + kq * 4 + r;
          ctx[(size_t)(b * S_LEN + s) * DMODEL + h * DK + dk] =
              (f16)(ov * il[rt][r]);
        }
      }
  }
}

extern "C" void kernel_launch(void* const* d_in, const int* in_sizes, int n_in,
                              void* d_out, int out_size, void* d_ws, size_t ws_size,
                              hipStream_t stream) {
  const float* q = (const float*)d_in[0];
  const float* k = (const float*)d_in[1];
  const float* v = (const float*)d_in[2];
  const int* mask = (const int*)d_in[3];
  const float* w_q = (const float*)d_in[4];
  const float* b_q = (const float*)d_in[5];
  const float* w_v = (const float*)d_in[6];
  const float* b_v = (const float*)d_in[7];
  const float* w_o = (const float*)d_in[8];
  const float* b_o = (const float*)d_in[9];

  float* out = (float*)d_out;
  float* attn = out + (size_t)BS * DMODEL;  // output 1 region

  // workspace (all f16): converted inputs, converted weights, intermediates
  f16* qf = (f16*)d_ws;                      // [BS][DMODEL]
  f16* kf = qf + (size_t)BS * DMODEL;
  f16* vf = kf + (size_t)BS * DMODEL;
  f16* wqf = vf + (size_t)BS * DMODEL;       // [DMODEL][DMODEL]
  f16* wvf = wqf + (size_t)DMODEL * DMODEL;
  f16* wof = wvf + (size_t)DMODEL * DMODEL;
  f16* qh = wof + (size_t)DMODEL * DMODEL;   // [B][H][S][DK] (pre-scaled 0.125)
  f16* kh = qh + (size_t)BS * DMODEL;        // [B][H][S][DK]
  f16* vhT = kh + (size_t)BS * DMODEL;       // [B][H][DK][S]
  f16* ctx = vhT + (size_t)BS * DMODEL;      // [BS][DMODEL]

  cvt6<<<dim3(4096, 6), 256, 0, stream>>>(q, k, v, w_q, w_v, w_o, qf, kf, vf,
                                          wqf, wvf, wof);
  qkv_gemm<<<dim3(8, 32, 3), 256, 0, stream>>>(qf, kf, vf, wqf, b_q, wvf, b_v,
                                               qh, kh, vhT);
  attn_fused<<<dim3(32, 32), 256, 0, stream>>>(qh, kh, vhT, mask, attn, ctx);
  gemm_out<<<dim3(8, 32), 256, 0, stream>>>(ctx, wof, b_o, out);
}